// Round 13
// baseline (548.264 us; speedup 1.0000x reference)
//
#include <hip/hip_runtime.h>
#include <math.h>

#define NN_NODES 4096
#define D_IN 128
#define D_H 256
#define KTOP 17
#define NEDGE (NN_NODES * KTOP)
#define INV_TEMP 5.0f
#define EPSV 1e-8f
#define CCAP 1024

typedef __bf16 bf16x8 __attribute__((ext_vector_type(8)));
typedef float f32x4 __attribute__((ext_vector_type(4)));

// last-block-tail counters (self-resetting; no spin, no barrier)
__device__ int g_tail1 = 0;
__device__ int g_tail2 = 0;
__device__ int g_tail3 = 0;

// ---------------- helpers ----------------
__device__ __forceinline__ float block_reduce_sum(float v, float* sb) {
#pragma unroll
    for (int o = 32; o > 0; o >>= 1) v += __shfl_down(v, o, 64);
    int wid = threadIdx.x >> 6;
    __syncthreads();
    if ((threadIdx.x & 63) == 0) sb[wid] = v;
    __syncthreads();
    return sb[0] + sb[1] + sb[2] + sb[3];
}

// fp32 -> bf16 (RNE)
__device__ __forceinline__ unsigned short f2bf(float x) {
    unsigned u = __float_as_uint(x);
    unsigned r = u + 0x7fff + ((u >> 16) & 1);
    return (unsigned short)(r >> 16);
}

__device__ __forceinline__ float bflo(unsigned x) { return __uint_as_float(x << 16); }
__device__ __forceinline__ float bfhi(unsigned x) { return __uint_as_float(x & 0xffff0000u); }

__device__ __forceinline__ float dot8bf(uint4 a, uint4 b) {
    float s = bflo(a.x) * bflo(b.x) + bfhi(a.x) * bfhi(b.x);
    s += bflo(a.y) * bflo(b.y) + bfhi(a.y) * bfhi(b.y);
    s += bflo(a.z) * bflo(b.z) + bfhi(a.z) * bfhi(b.z);
    s += bflo(a.w) * bflo(b.w) + bfhi(a.w) * bfhi(b.w);
    return s;
}

// async global -> LDS, 16 bytes per lane (wave-uniform LDS base + lane*16)
__device__ __forceinline__ void gl_lds16(const void* g, void* l) {
    __builtin_amdgcn_global_load_lds(
        (const __attribute__((address_space(1))) void*)(g),
        (__attribute__((address_space(3))) void*)(l), 16, 0, 0);
}

#define BARRIER_SB() do { __builtin_amdgcn_s_barrier(); __builtin_amdgcn_sched_barrier(0); } while (0)
#define WAITV(n) do { asm volatile("s_waitcnt vmcnt(" #n ")" ::: "memory"); __builtin_amdgcn_sched_barrier(0); } while (0)

// true if this block is the LAST of the grid to arrive here (release/acquire fenced)
__device__ __forceinline__ bool last_block(int* ctr, int* lastsh) {
    __syncthreads();
    if (threadIdx.x == 0) {
        __threadfence();
        *lastsh = (atomicAdd(ctr, 1) == (int)gridDim.x - 1) ? 1 : 0;
    }
    __syncthreads();
    if (*lastsh) {
        __threadfence();
        if (threadIdx.x == 0) atomicExch(ctr, 0);  // self-reset for next replay
        return true;
    }
    return false;
}

// ---------------- fused setup: x1 elementwise + zero(ECNT, FCNT, ZROW/PF/PB) ----------------
__global__ __launch_bounds__(256) void setup_kernel(const float* __restrict__ x,
                                                    const float* __restrict__ p_feat,
                                                    const float* __restrict__ p_shared,
                                                    float* __restrict__ x1,
                                                    int* __restrict__ ecnt,
                                                    int* __restrict__ fcnt,
                                                    float* __restrict__ zpp) {
    int i = blockIdx.x * 256 + threadIdx.x;
    if (i < NN_NODES * D_IN) {
        int c = i & (D_IN - 1);
        float v = x[i] * p_feat[c];
        v = fmaxf(v, 0.0f) * p_shared[c];
        x1[i] = v;
        return;
    }
    int z = i - NN_NODES * D_IN;
    if (z < NN_NODES) ecnt[z] = 0;
    else if (z < 2 * NN_NODES) fcnt[z - NN_NODES] = 0;
    else if (z < 5 * NN_NODES) zpp[z - 2 * NN_NODES] = 0.f;  // ZROW,PF,PB contiguous
}

// exclusive scan of 4096 counts -> ptr[4097]; zeroes cnt; optional dinv=rsqrt(1+cnt)
__device__ void scan_body(int* __restrict__ cnt, int* __restrict__ ptr, float* __restrict__ dinv) {
    __shared__ int tmp[256];
    int t = threadIdx.x;
    int base = t * 16;
    int c[16]; int local[16]; int s = 0;
#pragma unroll
    for (int u = 0; u < 16; ++u) { c[u] = cnt[base + u]; local[u] = s; s += c[u]; cnt[base + u] = 0; }
    if (dinv) {
#pragma unroll
        for (int u = 0; u < 16; ++u) dinv[base + u] = rsqrtf(1.0f + (float)c[u]);
    }
    tmp[t] = s;
    __syncthreads();
    for (int off = 1; off < 256; off <<= 1) {
        int v = (t >= off) ? tmp[t - off] : 0;
        __syncthreads();
        tmp[t] += v;
        __syncthreads();
    }
    int prefix = (t > 0) ? tmp[t - 1] : 0;
#pragma unroll
    for (int u = 0; u < 16; ++u) ptr[base + u] = prefix + local[u];
    if (t == 255) ptr[NN_NODES] = prefix + s;
}

// ---------------- indegree count; LAST block runs scan+dinv (no extra launch) ----------------
__global__ __launch_bounds__(256) void ecount_scan_kernel(const int* __restrict__ dst,
                                                          int* __restrict__ cnt, int E,
                                                          int* __restrict__ eptr,
                                                          float* __restrict__ dinv) {
    __shared__ int lastsh;
    int e = blockIdx.x * 256 + threadIdx.x;
    if (e < E) atomicAdd(&cnt[dst[e]], 1);
    if (last_block(&g_tail1, &lastsh))
        scan_body(cnt, eptr, dinv);
}

// ---------------- dual: CSR fill || x1s = dinv-scaled x1 (disjoint blocks) ----------------
__global__ __launch_bounds__(256) void efill_x1s_kernel(const int* __restrict__ src,
                                                        const int* __restrict__ dst,
                                                        const int* __restrict__ ptr,
                                                        int* __restrict__ cnt,
                                                        int* __restrict__ esrt, int E, int eblocks,
                                                        const float* __restrict__ x1,
                                                        const float* __restrict__ dinv,
                                                        float* __restrict__ x1s) {
    int b = blockIdx.x;
    if (b < eblocks) {
        int e = b * 256 + threadIdx.x;
        if (e >= E) return;
        int d = dst[e];
        int p = ptr[d] + atomicAdd(&cnt[d], 1);
        esrt[p] = src[e];
    } else {
        int i = (b - eblocks) * 256 + threadIdx.x;
        if (i < NN_NODES * D_IN) x1s[i] = dinv[i >> 7] * x1[i];
    }
}

// ---------------- ILP gather core (pre-scaled source): acc += sum hs[s*C+t] ----------------
template <int C>
__device__ __forceinline__ float gather_ns(const float* __restrict__ hs,
                                           const int* __restrict__ esrt, int p, int pe,
                                           int t, float acc) {
    for (; p + 16 <= pe; p += 16) {
        int s[16];
#pragma unroll
        for (int u = 0; u < 16; ++u) s[u] = esrt[p + u];
        float hv[16];
#pragma unroll
        for (int u = 0; u < 16; ++u) hv[u] = hs[(size_t)s[u] * C + t];
#pragma unroll
        for (int u = 0; u < 16; ++u) acc += hv[u];
    }
    for (; p + 4 <= pe; p += 4) {
        int s[4];
#pragma unroll
        for (int u = 0; u < 4; ++u) s[u] = esrt[p + u];
        float hv[4];
#pragma unroll
        for (int u = 0; u < 4; ++u) hv[u] = hs[(size_t)s[u] * C + t];
#pragma unroll
        for (int u = 0; u < 4; ++u) acc += hv[u];
    }
    for (; p < pe; ++p) acc += hs[(size_t)esrt[p] * C + t];
    return acc;
}

// ---------------- fused: agg gather + h/hn normalize -> bf16 ----------------
__global__ __launch_bounds__(256) void agg_hn_kernel(const float* __restrict__ x1,
                                                     const float* __restrict__ x1s,
                                                     const float* __restrict__ dinv,
                                                     const int* __restrict__ eptr,
                                                     const int* __restrict__ esrt,
                                                     const float* __restrict__ p_balance,
                                                     unsigned short* __restrict__ hn_bf) {
    __shared__ float sb[4];
    int n = blockIdx.x, t = threadIdx.x;
    float v;
    if (t < D_IN) {
        v = x1[(size_t)n * D_IN + t] * p_balance[t];
    } else {
        int c = t - D_IN;
        float acc = x1s[(size_t)n * D_IN + c];
        acc = gather_ns<D_IN>(x1s, esrt, eptr[n], eptr[n + 1], c, acc);
        v = dinv[n] * acc * p_balance[t];
    }
    float ss = block_reduce_sum(v * v, sb);
    float inv = 1.0f / (sqrtf(ss) + EPSV);
    hn_bf[(size_t)n * D_H + t] = f2bf(v * inv);
}

// ---------------- fused: rownorm both Z + diag dot ----------------
__global__ __launch_bounds__(256) void rownorm_diag_kernel(const float* __restrict__ Z1,
                                                           const float* __restrict__ Z2,
                                                           unsigned short* __restrict__ z1bf,
                                                           unsigned short* __restrict__ z2bf,
                                                           float* __restrict__ diag) {
    __shared__ float sb[4];
    int n = blockIdx.x, t = threadIdx.x;
    float v1 = Z1[(size_t)n * D_H + t];
    float v2 = Z2[(size_t)n * D_H + t];
    float ss1 = block_reduce_sum(v1 * v1, sb);
    float ss2 = block_reduce_sum(v2 * v2, sb);
    float i1 = 1.0f / (sqrtf(ss1) + EPSV);
    float i2 = 1.0f / (sqrtf(ss2) + EPSV);
    z1bf[(size_t)n * D_H + t] = f2bf(v1 * i1);
    z2bf[(size_t)n * D_H + t] = f2bf(v2 * i2);
    float d = block_reduce_sum((v1 * i1) * (v2 * i2), sb);
    if (t == 0) diag[n] = d;
}

// ---------------- fp32 GEMM body (optional dinv-scaled second output) ----------------
#define BM 64
#define BN 64
#define BK 16

__device__ void gemm_nn_body(const float* __restrict__ A, const float* __restrict__ B,
                             float* __restrict__ C, int Nn, int Kk, int m0, int n0,
                             const float* __restrict__ dscale, float* __restrict__ Cs) {
    __shared__ float As[BK][BM + 4];
    __shared__ float Bs[BK][BN + 4];
    const int tid = threadIdx.x;
    const int tx = tid & 15, ty = tid >> 4;
    const int arow = tid >> 2, acol = (tid & 3) << 2;
    const int brow = tid >> 4, bcol = (tid & 15) << 2;
    float acc[4][4] = {{0.f}};

    for (int k0 = 0; k0 < Kk; k0 += BK) {
        float4 av = *(const float4*)&A[(size_t)(m0 + arow) * Kk + k0 + acol];
        float4 bv = *(const float4*)&B[(size_t)(k0 + brow) * Nn + n0 + bcol];
        As[acol + 0][arow] = av.x;
        As[acol + 1][arow] = av.y;
        As[acol + 2][arow] = av.z;
        As[acol + 3][arow] = av.w;
        *(float4*)&Bs[brow][bcol] = bv;
        __syncthreads();
#pragma unroll
        for (int k = 0; k < BK; ++k) {
            float4 a = *(const float4*)&As[k][ty << 2];
            float4 b = *(const float4*)&Bs[k][tx << 2];
            acc[0][0] += a.x * b.x; acc[0][1] += a.x * b.y; acc[0][2] += a.x * b.z; acc[0][3] += a.x * b.w;
            acc[1][0] += a.y * b.x; acc[1][1] += a.y * b.y; acc[1][2] += a.y * b.z; acc[1][3] += a.y * b.w;
            acc[2][0] += a.z * b.x; acc[2][1] += a.z * b.y; acc[2][2] += a.z * b.z; acc[2][3] += a.z * b.w;
            acc[3][0] += a.w * b.x; acc[3][1] += a.w * b.y; acc[3][2] += a.w * b.z; acc[3][3] += a.w * b.w;
        }
        __syncthreads();
    }
#pragma unroll
    for (int i = 0; i < 4; ++i) {
        int m = m0 + (ty << 2) + i;
        *(float4*)&C[(size_t)m * Nn + n0 + (tx << 2)] = *(float4*)acc[i];
        if (Cs) {
            float d = dscale[m];
            float4 sv;
            sv.x = d * acc[i][0]; sv.y = d * acc[i][1];
            sv.z = d * acc[i][2]; sv.w = d * acc[i][3];
            *(float4*)&Cs[(size_t)m * Nn + n0 + (tx << 2)] = sv;
        }
    }
}

// two M=4096,N=256,K=256 GEMMs in one launch; first also emits dinv-scaled copy
__global__ __launch_bounds__(256) void gemm_nn2x_kernel(const float* __restrict__ A1,
                                                        const float* __restrict__ A2,
                                                        const float* __restrict__ B,
                                                        float* __restrict__ C1,
                                                        float* __restrict__ C2,
                                                        const float* __restrict__ dinv,
                                                        float* __restrict__ C1s) {
    int gy = blockIdx.y;
    bool first = (gy < NN_NODES / BM);
    const float* A = first ? A1 : A2;
    float* C = first ? C1 : C2;
    int m0 = (gy & (NN_NODES / BM - 1)) * BM;
    gemm_nn_body(A, B, C, D_H, D_H, m0, blockIdx.x * BN,
                 first ? dinv : nullptr, first ? C1s : nullptr);
}

// ---------------- MFMA NT GEMM: C[4096,4096] = X @ Y^T, K=256, single bf16 ----------------
// 256x256 tile, 8 waves, BK=64, dbuf 128 KB LDS, counted-vmcnt pipeline (T4),
// bijective XCD swizzle (T1).
// MODE 0: write C + per-row 32-col-group maxima (for hierarchical topk).
// MODE 1: zrow-only (row-sums of exp(5*S)).
template <int MODE>
__global__ __launch_bounds__(512) void gemm_nt_mfma(const unsigned short* __restrict__ Abf,
                                                    const unsigned short* __restrict__ Bbf,
                                                    float* __restrict__ C,
                                                    float* __restrict__ zrow,
                                                    float* __restrict__ rowgmax) {
    const int wg = (blockIdx.x & 7) * 32 + (blockIdx.x >> 3);
    const int bx = wg & 15, by = wg >> 4;

    __shared__ char lds[131072];
    const int tid = threadIdx.x;
    const int w = tid >> 6, lane = tid & 63;
    const int wr = w >> 2, wc = w & 3;
    const int m0 = by * 256, n0 = bx * 256;
    const int lrow = lane & 15, lquad = lane >> 4;

    f32x4 acc[8][4];
#pragma unroll
    for (int i = 0; i < 8; ++i)
#pragma unroll
        for (int j = 0; j < 4; ++j) acc[i][j] = (f32x4)(0.f);

    const char* Ag = (const char*)Abf + (size_t)m0 * 512;
    const char* Bg = (const char*)Bbf + (size_t)n0 * 512;

    const int ssub = ((lane & 7) << 4) ^ (((lane >> 3) & 7) << 4);
    auto stage = [&](int half, int k0) {
        char* Abuf = lds + half * 65536;
        char* Bbuf = Abuf + 32768;
#pragma unroll
        for (int ti = 0; ti < 4; ++ti) {
            int chunk = ti * 8 + w;
            int row = chunk * 8 + (lane >> 3);
            size_t gb = (size_t)row * 512 + (size_t)k0 * 2 + ssub;
            gl_lds16(Ag + gb, Abuf + chunk * 1024);
            gl_lds16(Bg + gb, Bbuf + chunk * 1024);
        }
    };

    auto compute = [&](int half) {
        const char* Abuf = lds + half * 65536;
        const char* Bbuf = Abuf + 32768;
#pragma unroll
        for (int ksub = 0; ksub < 2; ++ksub) {
            int co = (ksub * 64 + lquad * 16) ^ ((lrow & 7) << 4);
            bf16x8 a[8], b[4];
#pragma unroll
            for (int fi = 0; fi < 8; ++fi) {
                int row = wr * 128 + fi * 16 + lrow;
                a[fi] = __builtin_bit_cast(bf16x8, *(const uint4*)(Abuf + row * 128 + co));
            }
#pragma unroll
            for (int fj = 0; fj < 4; ++fj) {
                int row = wc * 64 + fj * 16 + lrow;
                b[fj] = __builtin_bit_cast(bf16x8, *(const uint4*)(Bbuf + row * 128 + co));
            }
#pragma unroll
            for (int fi = 0; fi < 8; ++fi)
#pragma unroll
                for (int fj = 0; fj < 4; ++fj)
                    acc[fi][fj] = __builtin_amdgcn_mfma_f32_16x16x32_bf16(a[fi], b[fj], acc[fi][fj], 0, 0, 0);
        }
    };

    stage(0, 0);
    stage(1, 64);
    WAITV(8); BARRIER_SB();
    compute(0);
    BARRIER_SB();
    stage(0, 128);
    WAITV(8); BARRIER_SB();
    compute(1);
    BARRIER_SB();
    stage(1, 192);
    WAITV(8); BARRIER_SB();
    compute(0);
    BARRIER_SB();
    WAITV(0); BARRIER_SB();
    compute(1);

    const int rq = (lane >> 4) * 4;
    if constexpr (MODE == 0) {
        const int c0 = lane & 3;
        const int cg = ((lane & 15) >> 2) << 2;
#pragma unroll
        for (int fi = 0; fi < 8; ++fi) {
            int row = m0 + wr * 128 + fi * 16 + rq + c0;
            float m16[4];
#pragma unroll
            for (int fj = 0; fj < 4; ++fj) {
                float a0 = acc[fi][fj][0], a1 = acc[fi][fj][1], a2 = acc[fi][fj][2], a3 = acc[fi][fj][3];
                float x0 = __shfl_xor(a1, 1, 64), x1 = __shfl_xor(a0, 1, 64);
                float x2 = __shfl_xor(a3, 1, 64), x3 = __shfl_xor(a2, 1, 64);
                bool odd = (c0 & 1) != 0;
                float t0 = odd ? x0 : a0;
                float t1 = odd ? a1 : x1;
                float t2 = odd ? x2 : a2;
                float t3 = odd ? a3 : x3;
                float y0 = __shfl_xor(t2, 2, 64), y2 = __shfl_xor(t0, 2, 64);
                float y1 = __shfl_xor(t3, 2, 64), y3 = __shfl_xor(t1, 2, 64);
                bool hi = (c0 & 2) != 0;
                f32x4 o;
                o[0] = hi ? y0 : t0;
                o[1] = hi ? y1 : t1;
                o[2] = hi ? t2 : y2;
                o[3] = hi ? t3 : y3;
                int cb = n0 + wc * 64 + fj * 16 + cg;
                *(f32x4*)&C[(size_t)row * NN_NODES + cb] = o;
                // per-(row, fj) 16-col max: reduce 4 regs, then across cg lanes (bits 2-3)
                float m4 = fmaxf(fmaxf(o[0], o[1]), fmaxf(o[2], o[3]));
                m4 = fmaxf(m4, __shfl_xor(m4, 4, 64));
                m4 = fmaxf(m4, __shfl_xor(m4, 8, 64));
                m16[fj] = m4;
            }
            if ((lane & 12) == 0) {
                int gbase = (n0 >> 5) + wc * 2;
                rowgmax[(size_t)row * 128 + gbase + 0] = fmaxf(m16[0], m16[1]);
                rowgmax[(size_t)row * 128 + gbase + 1] = fmaxf(m16[2], m16[3]);
            }
        }
    }
    if constexpr (MODE == 1) {
#pragma unroll
        for (int fi = 0; fi < 8; ++fi) {
            int rb = m0 + wr * 128 + fi * 16 + rq;
#pragma unroll
            for (int r = 0; r < 4; ++r) {
                float s = 0.f;
#pragma unroll
                for (int fj = 0; fj < 4; ++fj) s += __expf(INV_TEMP * acc[fi][fj][r]);
#pragma unroll
                for (int o = 1; o < 16; o <<= 1) s += __shfl_xor(s, o, 64);
                if ((lane & 15) == 0) atomicAdd(&zrow[rb + r], s);
            }
        }
    }
}

// ---------------- hierarchical top-k; LAST block also runs FCNT->RPTR scan ----------------
__global__ __launch_bounds__(256) void topk_kernel(const float* __restrict__ S,
                                                   const float* __restrict__ rowgmax,
                                                   float* __restrict__ vals,
                                                   int* __restrict__ idxo,
                                                   int* __restrict__ fcnt,
                                                   int* __restrict__ rptr) {
    __shared__ float gm[128];
    __shared__ float Tsh;
    __shared__ int ccnt;
    __shared__ float cv[CCAP];
    __shared__ int ci[CCAP];
    __shared__ float wvs[8];
    __shared__ int wis[8];
    __shared__ int lastsh;
    const int i = blockIdx.x, t = threadIdx.x;
    const int lane = t & 63, wid = t >> 6;
    const float* row = &S[(size_t)i * NN_NODES];

    if (t < 128) gm[t] = rowgmax[(size_t)i * 128 + t];
    if (t == 0) ccnt = 0;
    __syncthreads();

    // T = 17th largest of 128 group maxima (rank with index tie-break => unique)
    if (t < 128) {
        float g = gm[t];
        int rank = 0;
        for (int q = 0; q < 128; ++q) {
            float o = gm[q];
            if (o > g || (o == g && q < t)) rank++;
        }
        if (rank == 16) Tsh = g;
    }
    __syncthreads();
    const float T = Tsh;

    // gather candidates from groups with gmax >= T (8 threads/group, float4 each)
    for (int g = (t >> 3); g < 128; g += 32) {
        if (gm[g] >= T) {
            int base = g * 32 + (t & 7) * 4;
            float4 f = *(const float4*)&row[base];
            float vv[4] = {f.x, f.y, f.z, f.w};
#pragma unroll
            for (int u = 0; u < 4; ++u) {
                if (vv[u] >= T) {
                    int p = atomicAdd(&ccnt, 1);
                    if (p < CCAP) { cv[p] = vv[u]; ci[p] = base + u; }
                }
            }
        }
    }
    __syncthreads();
    const int cnt = ccnt;

    if (cnt <= CCAP) {
        for (int p = t; p < cnt; p += 256) {
            float mv = cv[p];
            int mi = ci[p];
            int r = 0;
            for (int q = 0; q < cnt; ++q) {
                float qv = cv[q];
                int qi = ci[q];
                if (qv > mv || (qv == mv && qi < mi)) r++;
            }
            if (r < KTOP) {
                vals[i * KTOP + r] = isnan(mv) ? 0.f : mv;
                idxo[i * KTOP + r] = mi;
                atomicAdd(&fcnt[mi], 1);
            }
        }
    } else {
        // fallback (near-impossible): exact iterative extraction from full row
        float v[16];
        int id[16];
#pragma unroll
        for (int u = 0; u < 4; ++u) {
            int base = u * 1024 + t * 4;
            float4 f = *(const float4*)&row[base];
            v[u * 4 + 0] = f.x; id[u * 4 + 0] = base + 0;
            v[u * 4 + 1] = f.y; id[u * 4 + 1] = base + 1;
            v[u * 4 + 2] = f.z; id[u * 4 + 2] = base + 2;
            v[u * 4 + 3] = f.w; id[u * 4 + 3] = base + 3;
        }
        float bv = v[0];
        int bi = id[0];
#pragma unroll
        for (int u = 1; u < 16; ++u)
            if (v[u] > bv || (v[u] == bv && id[u] < bi)) { bv = v[u]; bi = id[u]; }
        for (int k = 0; k < KTOP; ++k) {
            float mv = bv;
            int mi = bi;
#pragma unroll
            for (int o = 1; o < 64; o <<= 1) {
                float ov = __shfl_xor(mv, o, 64);
                int oi = __shfl_xor(mi, o, 64);
                if (ov > mv || (ov == mv && oi < mi)) { mv = ov; mi = oi; }
            }
            int slot = ((k & 1) << 2) + wid;
            if (lane == 0) { wvs[slot] = mv; wis[slot] = mi; }
            __syncthreads();
            int b0 = (k & 1) << 2;
            mv = wvs[b0]; mi = wis[b0];
#pragma unroll
            for (int ww = 1; ww < 4; ++ww) {
                float ov = wvs[b0 + ww];
                int oi = wis[b0 + ww];
                if (ov > mv || (ov == mv && oi < mi)) { mv = ov; mi = oi; }
            }
            if (t == 0) {
                vals[i * KTOP + k] = isnan(mv) ? 0.f : mv;
                idxo[i * KTOP + k] = mi;
                atomicAdd(&fcnt[mi], 1);
            }
            if (bi == mi) {
#pragma unroll
                for (int u = 0; u < 16; ++u)
                    if (id[u] == mi) v[u] = -INFINITY;
                bv = v[0]; bi = id[0];
#pragma unroll
                for (int u = 1; u < 16; ++u)
                    if (v[u] > bv || (v[u] == bv && id[u] < bi)) { bv = v[u]; bi = id[u]; }
            }
        }
    }

    // tail: last block scans FCNT -> RPTR (zeroes FCNT)
    if (last_block(&g_tail2, &lastsh))
        scan_body(fcnt, rptr, nullptr);
}

// ---------------- dual: fillrev+wedges || T1 = X1 @ W1 (+T1s) (no barrier, disjoint blocks) ----------------
#define EBLK ((NEDGE + 255) / 256)
__global__ __launch_bounds__(256) void dual_fillrev_gemm(const int* __restrict__ idx,
                                                         const float* __restrict__ vals,
                                                         const int* __restrict__ ptr,
                                                         int* __restrict__ fcnt,
                                                         int* __restrict__ rrow, int* __restrict__ rsrc,
                                                         float* __restrict__ wrev,
                                                         float* __restrict__ wfwd,
                                                         const float* __restrict__ X1,
                                                         const float* __restrict__ W1,
                                                         float* __restrict__ T1,
                                                         const float* __restrict__ dinv,
                                                         float* __restrict__ T1s) {
    int b = blockIdx.x;
    if (b < EBLK) {
        int e = b * 256 + threadIdx.x;
        if (e >= NEDGE) return;
        int i = e / KTOP;
        int j = idx[e];
        float a = vals[e];
        bool found = false;
        float bval = 0.f;
        const int* lj = &idx[j * KTOP];
#pragma unroll
        for (int k = 0; k < KTOP; ++k)
            if (lj[k] == i) { found = true; bval = vals[j * KTOP + k]; }
        float w = (a + (found ? bval : 0.f)) / (found ? 2.0f : 1.0f);
        wfwd[e] = w > 0.f ? w : 0.f;
        int p = ptr[j] + atomicAdd(&fcnt[j], 1);
        rrow[p] = j; rsrc[p] = i;
        wrev[p] = found ? 0.f : fmaxf(a, 0.f);
    } else {
        int tile = b - EBLK;  // 0..255
        int bx = tile & (D_H / BN - 1);
        int by = tile >> 2;
        gemm_nn_body(X1, W1, T1, D_H, D_IN, by * BM, bx * BN, dinv, T1s);
    }
}

// ---------------- dual prop/spmm rows ----------------
__device__ __forceinline__ void prop_row(float* __restrict__ out, const float* __restrict__ Xsd,
                                         const float* __restrict__ dinv, const int* __restrict__ eptr,
                                         const int* __restrict__ esrt, const float* __restrict__ bias,
                                         int n, int act) {
    int t = threadIdx.x;
    float acc = Xsd[(size_t)n * D_H + t];
    acc = gather_ns<D_H>(Xsd, esrt, eptr[n], eptr[n + 1], t, acc);
    acc = dinv[n] * acc + bias[t];
    if (act == 1) acc = fmaxf(acc, 0.f);
    else acc = acc > 0.f ? acc : expm1f(acc);
    out[(size_t)n * D_H + t] = acc;
}

__device__ __forceinline__ void spmm_row(float* __restrict__ out, const float* __restrict__ X,
                                         const int* __restrict__ idx, const float* __restrict__ wfwd,
                                         const int* __restrict__ ptr, const int* __restrict__ rsrc,
                                         const float* __restrict__ wrev, const float* __restrict__ bias,
                                         int i, int act) {
    int c = threadIdx.x;
    float acc = 0.f;
#pragma unroll
    for (int k = 0; k < KTOP; ++k) {
        int j = idx[i * KTOP + k];
        float w = wfwd[i * KTOP + k];
        acc += w * X[(size_t)j * D_H + c];
    }
    int p = ptr[i], pe = ptr[i + 1];
    for (; p + 8 <= pe; p += 8) {
        int s[8];
        float wv[8];
#pragma unroll
        for (int u = 0; u < 8; ++u) { s[u] = rsrc[p + u]; wv[u] = wrev[p + u]; }
        float xv[8];
#pragma unroll
        for (int u = 0; u < 8; ++u) xv[u] = X[(size_t)s[u] * D_H + c];
#pragma unroll
        for (int u = 0; u < 8; ++u) acc += wv[u] * xv[u];
    }
    for (; p < pe; ++p) {
        float w = wrev[p];
        if (w != 0.f) acc += w * X[(size_t)rsrc[p] * D_H + c];
    }
    acc += bias[c];
    if (act == 1) acc = fmaxf(acc, 0.f);
    else acc = acc > 0.f ? acc : expm1f(acc);
    out[(size_t)i * D_H + c] = acc;
}

__global__ __launch_bounds__(256) void dual_prop_spmm(const float* __restrict__ Xps,
                                                      const float* __restrict__ Xs,
                                                      const float* __restrict__ dinv,
                                                      const int* __restrict__ eptr,
                                                      const int* __restrict__ esrt,
                                                      const int* __restrict__ idx,
                                                      const float* __restrict__ wfwd,
                                                      const int* __restrict__ rptr,
                                                      const int* __restrict__ rsrc,
                                                      const float* __restrict__ wrev,
                                                      const float* __restrict__ bias,
                                                      float* __restrict__ out1,
                                                      float* __restrict__ out2,
                                                      int act) {
    int b = blockIdx.x;
    if (b < NN_NODES) prop_row(out1, Xps, dinv, eptr, esrt, bias, b, act);
    else spmm_row(out2, Xs, idx, wfwd, rptr, rsrc, wrev, bias, b - NN_NODES, act);
}

// ---------------- loss body (256 threads) ----------------
__device__ void loss_body(const float* __restrict__ diag, const float* __restrict__ zrow,
                          const float* __restrict__ pf, const float* __restrict__ pb,
                          float* __restrict__ out) {
    __shared__ float sb[4];
    int t = threadIdx.x;
    float s = 0.f;
    for (int i = t; i < NN_NODES; i += 256) {
        float p = expf(INV_TEMP * diag[i]) / zrow[i];
        s += -logf(fmaxf(p, EPSV));
        s += 0.5f * (-logf(fmaxf(pf[i], EPSV)) - logf(fmaxf(pb[i], EPSV)));
    }
    float tot = block_reduce_sum(s, sb);
    if (t == 0) out[0] = tot / (float)NN_NODES;
}

// ---------------- pf/pb edge dots; LAST block computes the loss ----------------
__global__ __launch_bounds__(256) void pfpb_loss_kernel(const unsigned short* __restrict__ z1,
                                                        const unsigned short* __restrict__ z2,
                                                        const int* __restrict__ idx,
                                                        const float* __restrict__ wfwd,
                                                        const int* __restrict__ rrow,
                                                        const int* __restrict__ rsrc,
                                                        const float* __restrict__ wrev,
                                                        const float* __restrict__ zrow,
                                                        float* __restrict__ pf, float* __restrict__ pb,
                                                        const float* __restrict__ diag,
                                                        float* __restrict__ out) {
    __shared__ int lastsh;
    int g = (blockIdx.x * 256 + threadIdx.x) >> 4;
    int l = threadIdx.x & 15;
    if (g < 2 * NEDGE) {
        int i, j;
        float wv;
        if (g < NEDGE) { i = g / KTOP; j = idx[g]; wv = wfwd[g]; }
        else { int e2 = g - NEDGE; i = rrow[e2]; j = rsrc[e2]; wv = wrev[e2]; }
        if (wv != 0.f) {  // uniform within the 16-lane edge group
            const uint4* a1 = (const uint4*)&z1[(size_t)i * D_H + l * 16];
            const uint4* b1 = (const uint4*)&z2[(size_t)j * D_H + l * 16];
            const uint4* a2 = (const uint4*)&z1[(size_t)j * D_H + l * 16];
            const uint4* b2 = (const uint4*)&z2[(size_t)i * D_H + l * 16];
            float s1 = dot8bf(a1[0], b1[0]) + dot8bf(a1[1], b1[1]);
            float s2 = dot8bf(a2[0], b2[0]) + dot8bf(a2[1], b2[1]);
#pragma unroll
            for (int o = 8; o > 0; o >>= 1) {
                s1 += __shfl_xor(s1, o, 64);
                s2 += __shfl_xor(s2, o, 64);
            }
            if (l == 0) {
                float pfv = expf(s1 * INV_TEMP) / zrow[i] * wv;
                float pbv = expf(s2 * INV_TEMP) / zrow[j] * wv;
                atomicAdd(&pf[i], pfv);
                atomicAdd(&pb[i], pbv);
            }
        }
    }
    // tail: last block computes the loss (all pf/pb atomics visible after fence)
    if (last_block(&g_tail3, &lastsh))
        loss_body(diag, zrow, pf, pb, out);
}

// ---------------- launch ----------------
extern "C" void kernel_launch(void* const* d_in, const int* in_sizes, int n_in,
                              void* d_out, int out_size, void* d_ws, size_t ws_size,
                              hipStream_t stream) {
    (void)n_in; (void)out_size; (void)ws_size;
    const float* x = (const float*)d_in[0];
    const int* esrc = (const int*)d_in[1];
    const int* edst = (const int*)d_in[2];
    const float* p_feat = (const float*)d_in[3];
    const float* p_shared = (const float*)d_in[4];
    const float* p_balance = (const float*)d_in[5];
    const float* W1 = (const float*)d_in[6];
    const float* b1 = (const float*)d_in[7];
    const float* W2 = (const float*)d_in[8];
    const float* b2 = (const float*)d_in[9];
    const int E = in_sizes[1];

    float* ws = (float*)d_ws;
    size_t off = 0;
    float* SIM = ws + off; off += (size_t)NN_NODES * NN_NODES;
    float* ROWGMAX = ws + off; off += (size_t)NN_NODES * 128;
    float* X1  = ws + off; off += (size_t)NN_NODES * D_IN;
    float* X1S = ws + off; off += (size_t)NN_NODES * D_IN;
    float* T1  = ws + off; off += (size_t)NN_NODES * D_H;
    float* T1S = ws + off; off += (size_t)NN_NODES * D_H;
    float* H1  = ws + off; off += (size_t)NN_NODES * D_H;
    float* T2  = ws + off; off += (size_t)NN_NODES * D_H;
    float* T2S = ws + off; off += (size_t)NN_NODES * D_H;
    float* T3  = ws + off; off += (size_t)NN_NODES * D_H;
    float* Z1  = ws + off; off += (size_t)NN_NODES * D_H;
    float* G1  = ws + off; off += (size_t)NN_NODES * D_H;
    float* Z2  = ws + off; off += (size_t)NN_NODES * D_H;
    float* DINV = ws + off; off += NN_NODES;
    float* VALS = ws + off; off += (size_t)NEDGE;
    int*   IDX  = (int*)(ws + off); off += (size_t)NEDGE;
    float* WFWD = ws + off; off += (size_t)NEDGE;
    int*   RPTR = (int*)(ws + off); off += NN_NODES + 1;
    int*   FCNT = (int*)(ws + off); off += NN_NODES;
    int*   RROW = (int*)(ws + off); off += (size_t)NEDGE;
    int*   RSRC = (int*)(ws + off); off += (size_t)NEDGE;
    float* WREV = ws + off; off += (size_t)NEDGE;
    float* ZROW = ws + off; off += NN_NODES;   // ZROW,PF,PB contiguous (zeroed together)
    float* PF = ws + off; off += NN_NODES;
    float* PB = ws + off; off += NN_NODES;
    float* DIAG = ws + off; off += NN_NODES;
    unsigned short* HNbf = (unsigned short*)(ws + off); off += (size_t)NN_NODES * D_H / 2;
    unsigned short* Z1bf = (unsigned short*)(ws + off); off += (size_t)NN_NODES * D_H / 2;
    unsigned short* Z2bf = (unsigned short*)(ws + off); off += (size_t)NN_NODES * D_H / 2;
    int* ECNT = (int*)(ws + off); off += NN_NODES;
    int* EPTR = (int*)(ws + off); off += NN_NODES + 1;
    int* ESRT = (int*)(ws + off); off += (size_t)E;

    const int EBi = (E + 255) / 256;

    // 1. setup: x1 + zero(ECNT, FCNT, ZROW/PF/PB)
    {
        int blocks = (NN_NODES * D_IN + 5 * NN_NODES + 255) / 256;
        setup_kernel<<<blocks, 256, 0, stream>>>(x, p_feat, p_shared, X1, ECNT, FCNT, ZROW);
    }
    // 2. indegree count; tail block runs scan+dinv
    ecount_scan_kernel<<<EBi, 256, 0, stream>>>(edst, ECNT, E, EPTR, DINV);
    // 3. CSR fill || x1s = dinv*x1  [disjoint blocks]
    {
        int xblocks = (NN_NODES * D_IN + 255) / 256;
        efill_x1s_kernel<<<EBi + xblocks, 256, 0, stream>>>(esrc, edst, EPTR, ECNT, ESRT, E, EBi,
                                                            X1, DINV, X1S);
    }
    // 4. agg gather (pre-scaled) + h/hn -> bf16
    agg_hn_kernel<<<NN_NODES, 256, 0, stream>>>(X1, X1S, DINV, EPTR, ESRT, p_balance, HNbf);
    // 5. sim = hn @ hn^T + per-row group maxima  (XCD-swizzled)
    gemm_nt_mfma<0><<<256, 512, 0, stream>>>(HNbf, HNbf, SIM, nullptr, ROWGMAX);
    // 6. hierarchical topk + fused indegree count; tail block scans FCNT -> RPTR
    topk_kernel<<<NN_NODES, 256, 0, stream>>>(SIM, ROWGMAX, VALS, IDX, FCNT, RPTR);
    // 7. fillrev+wedges || T1 = X1 @ W1 (+T1s)  [disjoint blocks]
    dual_fillrev_gemm<<<EBLK + 256, 256, 0, stream>>>(IDX, VALS, RPTR, FCNT, RROW, RSRC,
                                                      WREV, WFWD, X1, W1, T1, DINV, T1S);
    // 8. H1 = relu(prop(T1)+b1)  ||  G1 = relu(W@T1+b1)   [prop reads pre-scaled T1s]
    dual_prop_spmm<<<2 * NN_NODES, 256, 0, stream>>>(T1S, T1, DINV, EPTR, ESRT, IDX, WFWD,
                                                     RPTR, RSRC, WREV, b1, H1, G1, 1);
    // 9. T2 = H1 @ W2 (+T2s)  ||  T3 = G1 @ W2
    {
        dim3 g(D_H / BN, 2 * NN_NODES / BM);
        gemm_nn2x_kernel<<<g, 256, 0, stream>>>(H1, G1, W2, T2, T3, DINV, T2S);
    }
    // 10. Z1 = elu(prop(T2)+b2)  ||  Z2 = elu(W@T3+b2)   [prop reads pre-scaled T2s]
    dual_prop_spmm<<<2 * NN_NODES, 256, 0, stream>>>(T2S, T3, DINV, EPTR, ESRT, IDX, WFWD,
                                                     RPTR, RSRC, WREV, b2, Z1, Z2, 2);
    // 11. rownorm both -> bf16 + diag
    rownorm_diag_kernel<<<NN_NODES, 256, 0, stream>>>(Z1, Z2, Z1bf, Z2bf, DIAG);
    // 12. zrow: row-sums of exp(5 * z1n@z2n^T)  (XCD-swizzled)
    gemm_nt_mfma<1><<<256, 512, 0, stream>>>(Z1bf, Z2bf, nullptr, ZROW, nullptr);
    // 13. pf / pb; tail block computes the loss
    {
        int blocks = (2 * NEDGE * 16 + 255) / 256;
        pfpb_loss_kernel<<<blocks, 256, 0, stream>>>(Z1bf, Z2bf, IDX, WFWD, RROW, RSRC, WREV,
                                                     ZROW, PF, PB, DIAG, (float*)d_out);
    }
}

// Round 15
// 304.906 us; speedup vs baseline: 1.7981x; 1.7981x over previous
//
#include <hip/hip_runtime.h>
#include <math.h>

#define NN_NODES 4096
#define D_IN 128
#define D_H 256
#define KTOP 17
#define NEDGE (NN_NODES * KTOP)
#define INV_TEMP 5.0f
#define EPSV 1e-8f
#define CCAP 1024

typedef __bf16 bf16x8 __attribute__((ext_vector_type(8)));
typedef float f32x4 __attribute__((ext_vector_type(4)));

// ---------------- helpers ----------------
__device__ __forceinline__ float block_reduce_sum(float v, float* sb) {
#pragma unroll
    for (int o = 32; o > 0; o >>= 1) v += __shfl_down(v, o, 64);
    int wid = threadIdx.x >> 6;
    __syncthreads();
    if ((threadIdx.x & 63) == 0) sb[wid] = v;
    __syncthreads();
    return sb[0] + sb[1] + sb[2] + sb[3];
}

// three values reduced in one pass (one barrier round-trip instead of three)
__device__ __forceinline__ void block_reduce_sum3(float& a, float& b, float& c, float* sb) {
#pragma unroll
    for (int o = 32; o > 0; o >>= 1) {
        a += __shfl_down(a, o, 64);
        b += __shfl_down(b, o, 64);
        c += __shfl_down(c, o, 64);
    }
    int wid = threadIdx.x >> 6;
    if ((threadIdx.x & 63) == 0) { sb[wid] = a; sb[4 + wid] = b; sb[8 + wid] = c; }
    __syncthreads();
    a = sb[0] + sb[1] + sb[2] + sb[3];
    b = sb[4] + sb[5] + sb[6] + sb[7];
    c = sb[8] + sb[9] + sb[10] + sb[11];
}

// fp32 -> bf16 (RNE)
__device__ __forceinline__ unsigned short f2bf(float x) {
    unsigned u = __float_as_uint(x);
    unsigned r = u + 0x7fff + ((u >> 16) & 1);
    return (unsigned short)(r >> 16);
}

__device__ __forceinline__ float bflo(unsigned x) { return __uint_as_float(x << 16); }
__device__ __forceinline__ float bfhi(unsigned x) { return __uint_as_float(x & 0xffff0000u); }

__device__ __forceinline__ float dot8bf(uint4 a, uint4 b) {
    float s = bflo(a.x) * bflo(b.x) + bfhi(a.x) * bfhi(b.x);
    s += bflo(a.y) * bflo(b.y) + bfhi(a.y) * bfhi(b.y);
    s += bflo(a.z) * bflo(b.z) + bfhi(a.z) * bfhi(b.z);
    s += bflo(a.w) * bflo(b.w) + bfhi(a.w) * bfhi(b.w);
    return s;
}

// async global -> LDS, 16 bytes per lane (wave-uniform LDS base + lane*16)
__device__ __forceinline__ void gl_lds16(const void* g, void* l) {
    __builtin_amdgcn_global_load_lds(
        (const __attribute__((address_space(1))) void*)(g),
        (__attribute__((address_space(3))) void*)(l), 16, 0, 0);
}

#define BARRIER_SB() do { __builtin_amdgcn_s_barrier(); __builtin_amdgcn_sched_barrier(0); } while (0)
#define WAITV(n) do { asm volatile("s_waitcnt vmcnt(" #n ")" ::: "memory"); __builtin_amdgcn_sched_barrier(0); } while (0)

// ---------------- fused setup: x1 elementwise + zero(ECNT, FCNT, ZROW/PF/PB) ----------------
__global__ __launch_bounds__(256) void setup_kernel(const float* __restrict__ x,
                                                    const float* __restrict__ p_feat,
                                                    const float* __restrict__ p_shared,
                                                    float* __restrict__ x1,
                                                    int* __restrict__ ecnt,
                                                    int* __restrict__ fcnt,
                                                    float* __restrict__ zpp) {
    int i = blockIdx.x * 256 + threadIdx.x;
    if (i < NN_NODES * D_IN) {
        int c = i & (D_IN - 1);
        float v = x[i] * p_feat[c];
        v = fmaxf(v, 0.0f) * p_shared[c];
        x1[i] = v;
        return;
    }
    int z = i - NN_NODES * D_IN;
    if (z < NN_NODES) ecnt[z] = 0;
    else if (z < 2 * NN_NODES) fcnt[z - NN_NODES] = 0;
    else if (z < 5 * NN_NODES) zpp[z - 2 * NN_NODES] = 0.f;  // ZROW,PF,PB contiguous
}

// ---------------- input-graph CSR (keyed by dst) ----------------
__global__ __launch_bounds__(256) void ecount_kernel(const int* __restrict__ dst, int* __restrict__ cnt, int E) {
    int e = blockIdx.x * 256 + threadIdx.x;
    if (e < E) atomicAdd(&cnt[dst[e]], 1);
}

// exclusive scan of 4096 counts -> ptr[4097]; zeroes cnt; optional dinv=rsqrt(1+cnt)
__global__ __launch_bounds__(256) void scan_kernel(int* __restrict__ cnt, int* __restrict__ ptr,
                                                   float* __restrict__ dinv) {
    __shared__ int tmp[256];
    int t = threadIdx.x;
    int base = t * 16;
    int c[16]; int local[16]; int s = 0;
#pragma unroll
    for (int u = 0; u < 16; ++u) { c[u] = cnt[base + u]; local[u] = s; s += c[u]; cnt[base + u] = 0; }
    if (dinv) {
#pragma unroll
        for (int u = 0; u < 16; ++u) dinv[base + u] = rsqrtf(1.0f + (float)c[u]);
    }
    tmp[t] = s;
    __syncthreads();
    for (int off = 1; off < 256; off <<= 1) {
        int v = (t >= off) ? tmp[t - off] : 0;
        __syncthreads();
        tmp[t] += v;
        __syncthreads();
    }
    int prefix = (t > 0) ? tmp[t - 1] : 0;
#pragma unroll
    for (int u = 0; u < 16; ++u) ptr[base + u] = prefix + local[u];
    if (t == 255) ptr[NN_NODES] = prefix + s;
}

// ---------------- dual: CSR fill || x1s = dinv-scaled x1 (disjoint blocks) ----------------
__global__ __launch_bounds__(256) void efill_x1s_kernel(const int* __restrict__ src,
                                                        const int* __restrict__ dst,
                                                        const int* __restrict__ ptr,
                                                        int* __restrict__ cnt,
                                                        int* __restrict__ esrt, int E, int eblocks,
                                                        const float* __restrict__ x1,
                                                        const float* __restrict__ dinv,
                                                        float* __restrict__ x1s) {
    int b = blockIdx.x;
    if (b < eblocks) {
        int e = b * 256 + threadIdx.x;
        if (e >= E) return;
        int d = dst[e];
        int p = ptr[d] + atomicAdd(&cnt[d], 1);
        esrt[p] = src[e];
    } else {
        int i = (b - eblocks) * 256 + threadIdx.x;
        if (i < NN_NODES * D_IN) x1s[i] = dinv[i >> 7] * x1[i];
    }
}

// ---------------- ILP gather core (pre-scaled source): acc += sum hs[s*C+t] ----------------
template <int C>
__device__ __forceinline__ float gather_ns(const float* __restrict__ hs,
                                           const int* __restrict__ esrt, int p, int pe,
                                           int t, float acc) {
    for (; p + 16 <= pe; p += 16) {
        int s[16];
#pragma unroll
        for (int u = 0; u < 16; ++u) s[u] = esrt[p + u];
        float hv[16];
#pragma unroll
        for (int u = 0; u < 16; ++u) hv[u] = hs[(size_t)s[u] * C + t];
#pragma unroll
        for (int u = 0; u < 16; ++u) acc += hv[u];
    }
    for (; p + 4 <= pe; p += 4) {
        int s[4];
#pragma unroll
        for (int u = 0; u < 4; ++u) s[u] = esrt[p + u];
        float hv[4];
#pragma unroll
        for (int u = 0; u < 4; ++u) hv[u] = hs[(size_t)s[u] * C + t];
#pragma unroll
        for (int u = 0; u < 4; ++u) acc += hv[u];
    }
    for (; p < pe; ++p) acc += hs[(size_t)esrt[p] * C + t];
    return acc;
}

// ---------------- fused: agg gather + h/hn normalize -> bf16 ----------------
__global__ __launch_bounds__(256) void agg_hn_kernel(const float* __restrict__ x1,
                                                     const float* __restrict__ x1s,
                                                     const float* __restrict__ dinv,
                                                     const int* __restrict__ eptr,
                                                     const int* __restrict__ esrt,
                                                     const float* __restrict__ p_balance,
                                                     unsigned short* __restrict__ hn_bf) {
    __shared__ float sb[4];
    int n = blockIdx.x, t = threadIdx.x;
    float v;
    if (t < D_IN) {
        v = x1[(size_t)n * D_IN + t] * p_balance[t];
    } else {
        int c = t - D_IN;
        float acc = x1s[(size_t)n * D_IN + c];
        acc = gather_ns<D_IN>(x1s, esrt, eptr[n], eptr[n + 1], c, acc);
        v = dinv[n] * acc * p_balance[t];
    }
    float ss = block_reduce_sum(v * v, sb);
    float inv = 1.0f / (sqrtf(ss) + EPSV);
    hn_bf[(size_t)n * D_H + t] = f2bf(v * inv);
}

// ---------------- fused: rownorm both Z + diag dot (single 3-way reduction) ----------------
__global__ __launch_bounds__(256) void rownorm_diag_kernel(const float* __restrict__ Z1,
                                                           const float* __restrict__ Z2,
                                                           unsigned short* __restrict__ z1bf,
                                                           unsigned short* __restrict__ z2bf,
                                                           float* __restrict__ diag) {
    __shared__ float sb[12];
    int n = blockIdx.x, t = threadIdx.x;
    float v1 = Z1[(size_t)n * D_H + t];
    float v2 = Z2[(size_t)n * D_H + t];
    float ss1 = v1 * v1, ss2 = v2 * v2, s12 = v1 * v2;
    block_reduce_sum3(ss1, ss2, s12, sb);
    float i1 = 1.0f / (sqrtf(ss1) + EPSV);
    float i2 = 1.0f / (sqrtf(ss2) + EPSV);
    z1bf[(size_t)n * D_H + t] = f2bf(v1 * i1);
    z2bf[(size_t)n * D_H + t] = f2bf(v2 * i2);
    if (t == 0) diag[n] = s12 * i1 * i2;
}

// ---------------- fp32 GEMM body (optional dinv-scaled second output) ----------------
#define BM 64
#define BN 64
#define BK 16

__device__ void gemm_nn_body(const float* __restrict__ A, const float* __restrict__ B,
                             float* __restrict__ C, int Nn, int Kk, int m0, int n0,
                             const float* __restrict__ dscale, float* __restrict__ Cs) {
    __shared__ float As[BK][BM + 4];
    __shared__ float Bs[BK][BN + 4];
    const int tid = threadIdx.x;
    const int tx = tid & 15, ty = tid >> 4;
    const int arow = tid >> 2, acol = (tid & 3) << 2;
    const int brow = tid >> 4, bcol = (tid & 15) << 2;
    float acc[4][4] = {{0.f}};

    for (int k0 = 0; k0 < Kk; k0 += BK) {
        float4 av = *(const float4*)&A[(size_t)(m0 + arow) * Kk + k0 + acol];
        float4 bv = *(const float4*)&B[(size_t)(k0 + brow) * Nn + n0 + bcol];
        As[acol + 0][arow] = av.x;
        As[acol + 1][arow] = av.y;
        As[acol + 2][arow] = av.z;
        As[acol + 3][arow] = av.w;
        *(float4*)&Bs[brow][bcol] = bv;
        __syncthreads();
#pragma unroll
        for (int k = 0; k < BK; ++k) {
            float4 a = *(const float4*)&As[k][ty << 2];
            float4 b = *(const float4*)&Bs[k][tx << 2];
            acc[0][0] += a.x * b.x; acc[0][1] += a.x * b.y; acc[0][2] += a.x * b.z; acc[0][3] += a.x * b.w;
            acc[1][0] += a.y * b.x; acc[1][1] += a.y * b.y; acc[1][2] += a.y * b.z; acc[1][3] += a.y * b.w;
            acc[2][0] += a.z * b.x; acc[2][1] += a.z * b.y; acc[2][2] += a.z * b.z; acc[2][3] += a.z * b.w;
            acc[3][0] += a.w * b.x; acc[3][1] += a.w * b.y; acc[3][2] += a.w * b.z; acc[3][3] += a.w * b.w;
        }
        __syncthreads();
    }
#pragma unroll
    for (int i = 0; i < 4; ++i) {
        int m = m0 + (ty << 2) + i;
        *(float4*)&C[(size_t)m * Nn + n0 + (tx << 2)] = *(float4*)acc[i];
        if (Cs) {
            float d = dscale[m];
            float4 sv;
            sv.x = d * acc[i][0]; sv.y = d * acc[i][1];
            sv.z = d * acc[i][2]; sv.w = d * acc[i][3];
            *(float4*)&Cs[(size_t)m * Nn + n0 + (tx << 2)] = sv;
        }
    }
}

// two M=4096,N=256,K=256 GEMMs in one launch; first also emits dinv-scaled copy
__global__ __launch_bounds__(256) void gemm_nn2x_kernel(const float* __restrict__ A1,
                                                        const float* __restrict__ A2,
                                                        const float* __restrict__ B,
                                                        float* __restrict__ C1,
                                                        float* __restrict__ C2,
                                                        const float* __restrict__ dinv,
                                                        float* __restrict__ C1s) {
    int gy = blockIdx.y;
    bool first = (gy < NN_NODES / BM);
    const float* A = first ? A1 : A2;
    float* C = first ? C1 : C2;
    int m0 = (gy & (NN_NODES / BM - 1)) * BM;
    gemm_nn_body(A, B, C, D_H, D_H, m0, blockIdx.x * BN,
                 first ? dinv : nullptr, first ? C1s : nullptr);
}

// ---------------- MFMA NT GEMM: C[4096,4096] = X @ Y^T, K=256, single bf16 ----------------
// 256x256 tile, 8 waves, BK=64, dbuf 128 KB LDS, counted-vmcnt pipeline (T4),
// bijective XCD swizzle (T1).
// MODE 0: write C + per-row 32-col-group maxima (for hierarchical topk).
// MODE 1: zrow-only (row-sums of exp(5*S)).
template <int MODE>
__global__ __launch_bounds__(512) void gemm_nt_mfma(const unsigned short* __restrict__ Abf,
                                                    const unsigned short* __restrict__ Bbf,
                                                    float* __restrict__ C,
                                                    float* __restrict__ zrow,
                                                    float* __restrict__ rowgmax) {
    const int wg = (blockIdx.x & 7) * 32 + (blockIdx.x >> 3);
    const int bx = wg & 15, by = wg >> 4;

    __shared__ char lds[131072];
    const int tid = threadIdx.x;
    const int w = tid >> 6, lane = tid & 63;
    const int wr = w >> 2, wc = w & 3;
    const int m0 = by * 256, n0 = bx * 256;
    const int lrow = lane & 15, lquad = lane >> 4;

    f32x4 acc[8][4];
#pragma unroll
    for (int i = 0; i < 8; ++i)
#pragma unroll
        for (int j = 0; j < 4; ++j) acc[i][j] = (f32x4)(0.f);

    const char* Ag = (const char*)Abf + (size_t)m0 * 512;
    const char* Bg = (const char*)Bbf + (size_t)n0 * 512;

    const int ssub = ((lane & 7) << 4) ^ (((lane >> 3) & 7) << 4);
    auto stage = [&](int half, int k0) {
        char* Abuf = lds + half * 65536;
        char* Bbuf = Abuf + 32768;
#pragma unroll
        for (int ti = 0; ti < 4; ++ti) {
            int chunk = ti * 8 + w;
            int row = chunk * 8 + (lane >> 3);
            size_t gb = (size_t)row * 512 + (size_t)k0 * 2 + ssub;
            gl_lds16(Ag + gb, Abuf + chunk * 1024);
            gl_lds16(Bg + gb, Bbuf + chunk * 1024);
        }
    };

    auto compute = [&](int half) {
        const char* Abuf = lds + half * 65536;
        const char* Bbuf = Abuf + 32768;
#pragma unroll
        for (int ksub = 0; ksub < 2; ++ksub) {
            int co = (ksub * 64 + lquad * 16) ^ ((lrow & 7) << 4);
            bf16x8 a[8], b[4];
#pragma unroll
            for (int fi = 0; fi < 8; ++fi) {
                int row = wr * 128 + fi * 16 + lrow;
                a[fi] = __builtin_bit_cast(bf16x8, *(const uint4*)(Abuf + row * 128 + co));
            }
#pragma unroll
            for (int fj = 0; fj < 4; ++fj) {
                int row = wc * 64 + fj * 16 + lrow;
                b[fj] = __builtin_bit_cast(bf16x8, *(const uint4*)(Bbuf + row * 128 + co));
            }
#pragma unroll
            for (int fi = 0; fi < 8; ++fi)
#pragma unroll
                for (int fj = 0; fj < 4; ++fj)
                    acc[fi][fj] = __builtin_amdgcn_mfma_f32_16x16x32_bf16(a[fi], b[fj], acc[fi][fj], 0, 0, 0);
        }
    };

    stage(0, 0);
    stage(1, 64);
    WAITV(8); BARRIER_SB();
    compute(0);
    BARRIER_SB();
    stage(0, 128);
    WAITV(8); BARRIER_SB();
    compute(1);
    BARRIER_SB();
    stage(1, 192);
    WAITV(8); BARRIER_SB();
    compute(0);
    BARRIER_SB();
    WAITV(0); BARRIER_SB();
    compute(1);

    const int rq = (lane >> 4) * 4;
    if constexpr (MODE == 0) {
        const int c0 = lane & 3;
        const int cg = ((lane & 15) >> 2) << 2;
#pragma unroll
        for (int fi = 0; fi < 8; ++fi) {
            int row = m0 + wr * 128 + fi * 16 + rq + c0;
            float m16[4];
#pragma unroll
            for (int fj = 0; fj < 4; ++fj) {
                float a0 = acc[fi][fj][0], a1 = acc[fi][fj][1], a2 = acc[fi][fj][2], a3 = acc[fi][fj][3];
                float x0 = __shfl_xor(a1, 1, 64), x1 = __shfl_xor(a0, 1, 64);
                float x2 = __shfl_xor(a3, 1, 64), x3 = __shfl_xor(a2, 1, 64);
                bool odd = (c0 & 1) != 0;
                float t0 = odd ? x0 : a0;
                float t1 = odd ? a1 : x1;
                float t2 = odd ? x2 : a2;
                float t3 = odd ? a3 : x3;
                float y0 = __shfl_xor(t2, 2, 64), y2 = __shfl_xor(t0, 2, 64);
                float y1 = __shfl_xor(t3, 2, 64), y3 = __shfl_xor(t1, 2, 64);
                bool hi = (c0 & 2) != 0;
                f32x4 o;
                o[0] = hi ? y0 : t0;
                o[1] = hi ? y1 : t1;
                o[2] = hi ? t2 : y2;
                o[3] = hi ? t3 : y3;
                int cb = n0 + wc * 64 + fj * 16 + cg;
                *(f32x4*)&C[(size_t)row * NN_NODES + cb] = o;
                // per-(row, fj) 16-col max: reduce 4 regs, then across cg lanes (bits 2-3)
                float m4 = fmaxf(fmaxf(o[0], o[1]), fmaxf(o[2], o[3]));
                m4 = fmaxf(m4, __shfl_xor(m4, 4, 64));
                m4 = fmaxf(m4, __shfl_xor(m4, 8, 64));
                m16[fj] = m4;
            }
            if ((lane & 12) == 0) {
                int gbase = (n0 >> 5) + wc * 2;
                rowgmax[(size_t)row * 128 + gbase + 0] = fmaxf(m16[0], m16[1]);
                rowgmax[(size_t)row * 128 + gbase + 1] = fmaxf(m16[2], m16[3]);
            }
        }
    }
    if constexpr (MODE == 1) {
#pragma unroll
        for (int fi = 0; fi < 8; ++fi) {
            int rb = m0 + wr * 128 + fi * 16 + rq;
#pragma unroll
            for (int r = 0; r < 4; ++r) {
                float s = 0.f;
#pragma unroll
                for (int fj = 0; fj < 4; ++fj) s += __expf(INV_TEMP * acc[fi][fj][r]);
#pragma unroll
                for (int o = 1; o < 16; o <<= 1) s += __shfl_xor(s, o, 64);
                if ((lane & 15) == 0) atomicAdd(&zrow[rb + r], s);
            }
        }
    }
}

// ---------------- hierarchical top-k using GEMM-emitted 32-col-group maxima ----------------
__global__ __launch_bounds__(256) void topk_kernel(const float* __restrict__ S,
                                                   const float* __restrict__ rowgmax,
                                                   float* __restrict__ vals,
                                                   int* __restrict__ idxo,
                                                   int* __restrict__ fcnt) {
    __shared__ float gm[128];
    __shared__ float Tsh;
    __shared__ int ccnt;
    __shared__ float cv[CCAP];
    __shared__ int ci[CCAP];
    __shared__ float wvs[8];
    __shared__ int wis[8];
    const int i = blockIdx.x, t = threadIdx.x;
    const int lane = t & 63, wid = t >> 6;
    const float* row = &S[(size_t)i * NN_NODES];

    if (t < 128) gm[t] = rowgmax[(size_t)i * 128 + t];
    if (t == 0) ccnt = 0;
    __syncthreads();

    // T = 17th largest of 128 group maxima (rank with index tie-break => unique)
    if (t < 128) {
        float g = gm[t];
        int rank = 0;
        for (int q = 0; q < 128; ++q) {
            float o = gm[q];
            if (o > g || (o == g && q < t)) rank++;
        }
        if (rank == 16) Tsh = g;
    }
    __syncthreads();
    const float T = Tsh;

    // gather candidates from groups with gmax >= T (8 threads/group, float4 each)
    for (int g = (t >> 3); g < 128; g += 32) {
        if (gm[g] >= T) {
            int base = g * 32 + (t & 7) * 4;
            float4 f = *(const float4*)&row[base];
            float vv[4] = {f.x, f.y, f.z, f.w};
#pragma unroll
            for (int u = 0; u < 4; ++u) {
                if (vv[u] >= T) {
                    int p = atomicAdd(&ccnt, 1);
                    if (p < CCAP) { cv[p] = vv[u]; ci[p] = base + u; }
                }
            }
        }
    }
    __syncthreads();
    const int cnt = ccnt;

    if (cnt <= CCAP) {
        for (int p = t; p < cnt; p += 256) {
            float mv = cv[p];
            int mi = ci[p];
            int r = 0;
            for (int q = 0; q < cnt; ++q) {
                float qv = cv[q];
                int qi = ci[q];
                if (qv > mv || (qv == mv && qi < mi)) r++;
            }
            if (r < KTOP) {
                vals[i * KTOP + r] = isnan(mv) ? 0.f : mv;
                idxo[i * KTOP + r] = mi;
                atomicAdd(&fcnt[mi], 1);
            }
        }
    } else {
        // fallback (near-impossible): exact iterative extraction from full row
        float v[16];
        int id[16];
#pragma unroll
        for (int u = 0; u < 4; ++u) {
            int base = u * 1024 + t * 4;
            float4 f = *(const float4*)&row[base];
            v[u * 4 + 0] = f.x; id[u * 4 + 0] = base + 0;
            v[u * 4 + 1] = f.y; id[u * 4 + 1] = base + 1;
            v[u * 4 + 2] = f.z; id[u * 4 + 2] = base + 2;
            v[u * 4 + 3] = f.w; id[u * 4 + 3] = base + 3;
        }
        float bv = v[0];
        int bi = id[0];
#pragma unroll
        for (int u = 1; u < 16; ++u)
            if (v[u] > bv || (v[u] == bv && id[u] < bi)) { bv = v[u]; bi = id[u]; }
        for (int k = 0; k < KTOP; ++k) {
            float mv = bv;
            int mi = bi;
#pragma unroll
            for (int o = 1; o < 64; o <<= 1) {
                float ov = __shfl_xor(mv, o, 64);
                int oi = __shfl_xor(mi, o, 64);
                if (ov > mv || (ov == mv && oi < mi)) { mv = ov; mi = oi; }
            }
            int slot = ((k & 1) << 2) + wid;
            if (lane == 0) { wvs[slot] = mv; wis[slot] = mi; }
            __syncthreads();
            int b0 = (k & 1) << 2;
            mv = wvs[b0]; mi = wis[b0];
#pragma unroll
            for (int ww = 1; ww < 4; ++ww) {
                float ov = wvs[b0 + ww];
                int oi = wis[b0 + ww];
                if (ov > mv || (ov == mv && oi < mi)) { mv = ov; mi = oi; }
            }
            if (t == 0) {
                vals[i * KTOP + k] = isnan(mv) ? 0.f : mv;
                idxo[i * KTOP + k] = mi;
                atomicAdd(&fcnt[mi], 1);
            }
            if (bi == mi) {
#pragma unroll
                for (int u = 0; u < 16; ++u)
                    if (id[u] == mi) v[u] = -INFINITY;
                bv = v[0]; bi = id[0];
#pragma unroll
                for (int u = 1; u < 16; ++u)
                    if (v[u] > bv || (v[u] == bv && id[u] < bi)) { bv = v[u]; bi = id[u]; }
            }
        }
    }
}

// ---------------- dual: fillrev+wedges || T1 = X1 @ W1 (+T1s) (no barrier, disjoint blocks) ----------------
#define EBLK ((NEDGE + 255) / 256)
__global__ __launch_bounds__(256) void dual_fillrev_gemm(const int* __restrict__ idx,
                                                         const float* __restrict__ vals,
                                                         const int* __restrict__ ptr,
                                                         int* __restrict__ fcnt,
                                                         int* __restrict__ rrow, int* __restrict__ rsrc,
                                                         float* __restrict__ wrev,
                                                         float* __restrict__ wfwd,
                                                         const float* __restrict__ X1,
                                                         const float* __restrict__ W1,
                                                         float* __restrict__ T1,
                                                         const float* __restrict__ dinv,
                                                         float* __restrict__ T1s) {
    int b = blockIdx.x;
    if (b < EBLK) {
        int e = b * 256 + threadIdx.x;
        if (e >= NEDGE) return;
        int i = e / KTOP;
        int j = idx[e];
        float a = vals[e];
        bool found = false;
        float bval = 0.f;
        const int* lj = &idx[j * KTOP];
#pragma unroll
        for (int k = 0; k < KTOP; ++k)
            if (lj[k] == i) { found = true; bval = vals[j * KTOP + k]; }
        float w = (a + (found ? bval : 0.f)) / (found ? 2.0f : 1.0f);
        wfwd[e] = w > 0.f ? w : 0.f;
        int p = ptr[j] + atomicAdd(&fcnt[j], 1);
        rrow[p] = j; rsrc[p] = i;
        wrev[p] = found ? 0.f : fmaxf(a, 0.f);
    } else {
        int tile = b - EBLK;  // 0..255
        int bx = tile & (D_H / BN - 1);
        int by = tile >> 2;
        gemm_nn_body(X1, W1, T1, D_H, D_IN, by * BM, bx * BN, dinv, T1s);
    }
}

// ---------------- dual prop/spmm rows ----------------
__device__ __forceinline__ void prop_row(float* __restrict__ out, const float* __restrict__ Xsd,
                                         const float* __restrict__ dinv, const int* __restrict__ eptr,
                                         const int* __restrict__ esrt, const float* __restrict__ bias,
                                         int n, int act) {
    int t = threadIdx.x;
    float acc = Xsd[(size_t)n * D_H + t];
    acc = gather_ns<D_H>(Xsd, esrt, eptr[n], eptr[n + 1], t, acc);
    acc = dinv[n] * acc + bias[t];
    if (act == 1) acc = fmaxf(acc, 0.f);
    else acc = acc > 0.f ? acc : expm1f(acc);
    out[(size_t)n * D_H + t] = acc;
}

__device__ __forceinline__ void spmm_row(float* __restrict__ out, const float* __restrict__ X,
                                         const int* __restrict__ idx, const float* __restrict__ wfwd,
                                         const int* __restrict__ ptr, const int* __restrict__ rsrc,
                                         const float* __restrict__ wrev, const float* __restrict__ bias,
                                         int i, int act) {
    int c = threadIdx.x;
    float acc = 0.f;
#pragma unroll
    for (int k = 0; k < KTOP; ++k) {
        int j = idx[i * KTOP + k];
        float w = wfwd[i * KTOP + k];
        acc += w * X[(size_t)j * D_H + c];
    }
    int p = ptr[i], pe = ptr[i + 1];
    for (; p + 8 <= pe; p += 8) {
        int s[8];
        float wv[8];
#pragma unroll
        for (int u = 0; u < 8; ++u) { s[u] = rsrc[p + u]; wv[u] = wrev[p + u]; }
        float xv[8];
#pragma unroll
        for (int u = 0; u < 8; ++u) xv[u] = X[(size_t)s[u] * D_H + c];
#pragma unroll
        for (int u = 0; u < 8; ++u) acc += wv[u] * xv[u];
    }
    for (; p < pe; ++p) {
        float w = wrev[p];
        if (w != 0.f) acc += w * X[(size_t)rsrc[p] * D_H + c];
    }
    acc += bias[c];
    if (act == 1) acc = fmaxf(acc, 0.f);
    else acc = acc > 0.f ? acc : expm1f(acc);
    out[(size_t)i * D_H + c] = acc;
}

__global__ __launch_bounds__(256) void dual_prop_spmm(const float* __restrict__ Xps,
                                                      const float* __restrict__ Xs,
                                                      const float* __restrict__ dinv,
                                                      const int* __restrict__ eptr,
                                                      const int* __restrict__ esrt,
                                                      const int* __restrict__ idx,
                                                      const float* __restrict__ wfwd,
                                                      const int* __restrict__ rptr,
                                                      const int* __restrict__ rsrc,
                                                      const float* __restrict__ wrev,
                                                      const float* __restrict__ bias,
                                                      float* __restrict__ out1,
                                                      float* __restrict__ out2,
                                                      int act) {
    int b = blockIdx.x;
    if (b < NN_NODES) prop_row(out1, Xps, dinv, eptr, esrt, bias, b, act);
    else spmm_row(out2, Xs, idx, wfwd, rptr, rsrc, wrev, bias, b - NN_NODES, act);
}

// ---------------- pf/pb (edge dots from L2-resident bf16 rows) ----------------
__global__ __launch_bounds__(256) void pfpb_edges(const unsigned short* __restrict__ z1,
                                                  const unsigned short* __restrict__ z2,
                                                  const int* __restrict__ idx,
                                                  const float* __restrict__ wfwd,
                                                  const int* __restrict__ rrow,
                                                  const int* __restrict__ rsrc,
                                                  const float* __restrict__ wrev,
                                                  const float* __restrict__ zrow,
                                                  float* __restrict__ pf, float* __restrict__ pb) {
    int g = (blockIdx.x * 256 + threadIdx.x) >> 4;
    int l = threadIdx.x & 15;
    if (g >= 2 * NEDGE) return;
    int i, j;
    float wv;
    if (g < NEDGE) { i = g / KTOP; j = idx[g]; wv = wfwd[g]; }
    else { int e2 = g - NEDGE; i = rrow[e2]; j = rsrc[e2]; wv = wrev[e2]; }
    if (wv == 0.f) return;
    const uint4* a1 = (const uint4*)&z1[(size_t)i * D_H + l * 16];
    const uint4* b1 = (const uint4*)&z2[(size_t)j * D_H + l * 16];
    const uint4* a2 = (const uint4*)&z1[(size_t)j * D_H + l * 16];
    const uint4* b2 = (const uint4*)&z2[(size_t)i * D_H + l * 16];
    float s1 = dot8bf(a1[0], b1[0]) + dot8bf(a1[1], b1[1]);
    float s2 = dot8bf(a2[0], b2[0]) + dot8bf(a2[1], b2[1]);
#pragma unroll
    for (int o = 8; o > 0; o >>= 1) {
        s1 += __shfl_xor(s1, o, 64);
        s2 += __shfl_xor(s2, o, 64);
    }
    if (l == 0) {
        float pfv = expf(s1 * INV_TEMP) / zrow[i] * wv;
        float pbv = expf(s2 * INV_TEMP) / zrow[j] * wv;
        atomicAdd(&pf[i], pfv);
        atomicAdd(&pb[i], pbv);
    }
}

__global__ __launch_bounds__(256) void loss_kernel(const float* __restrict__ diag,
                                                   const float* __restrict__ zrow,
                                                   const float* __restrict__ pf,
                                                   const float* __restrict__ pb,
                                                   float* __restrict__ out) {
    __shared__ float sb[4];
    int t = threadIdx.x;
    float s = 0.f;
    for (int i = t; i < NN_NODES; i += 256) {
        float p = expf(INV_TEMP * diag[i]) / zrow[i];
        s += -logf(fmaxf(p, EPSV));
        s += 0.5f * (-logf(fmaxf(pf[i], EPSV)) - logf(fmaxf(pb[i], EPSV)));
    }
    float tot = block_reduce_sum(s, sb);
    if (t == 0) out[0] = tot / (float)NN_NODES;
}

// ---------------- launch ----------------
extern "C" void kernel_launch(void* const* d_in, const int* in_sizes, int n_in,
                              void* d_out, int out_size, void* d_ws, size_t ws_size,
                              hipStream_t stream) {
    (void)n_in; (void)out_size; (void)ws_size;
    const float* x = (const float*)d_in[0];
    const int* esrc = (const int*)d_in[1];
    const int* edst = (const int*)d_in[2];
    const float* p_feat = (const float*)d_in[3];
    const float* p_shared = (const float*)d_in[4];
    const float* p_balance = (const float*)d_in[5];
    const float* W1 = (const float*)d_in[6];
    const float* b1 = (const float*)d_in[7];
    const float* W2 = (const float*)d_in[8];
    const float* b2 = (const float*)d_in[9];
    const int E = in_sizes[1];

    float* ws = (float*)d_ws;
    size_t off = 0;
    float* SIM = ws + off; off += (size_t)NN_NODES * NN_NODES;
    float* ROWGMAX = ws + off; off += (size_t)NN_NODES * 128;
    float* X1  = ws + off; off += (size_t)NN_NODES * D_IN;
    float* X1S = ws + off; off += (size_t)NN_NODES * D_IN;
    float* T1  = ws + off; off += (size_t)NN_NODES * D_H;
    float* T1S = ws + off; off += (size_t)NN_NODES * D_H;
    float* H1  = ws + off; off += (size_t)NN_NODES * D_H;
    float* T2  = ws + off; off += (size_t)NN_NODES * D_H;
    float* T2S = ws + off; off += (size_t)NN_NODES * D_H;
    float* T3  = ws + off; off += (size_t)NN_NODES * D_H;
    float* Z1  = ws + off; off += (size_t)NN_NODES * D_H;
    float* G1  = ws + off; off += (size_t)NN_NODES * D_H;
    float* Z2  = ws + off; off += (size_t)NN_NODES * D_H;
    float* DINV = ws + off; off += NN_NODES;
    float* VALS = ws + off; off += (size_t)NEDGE;
    int*   IDX  = (int*)(ws + off); off += (size_t)NEDGE;
    float* WFWD = ws + off; off += (size_t)NEDGE;
    int*   RPTR = (int*)(ws + off); off += NN_NODES + 1;
    int*   FCNT = (int*)(ws + off); off += NN_NODES;
    int*   RROW = (int*)(ws + off); off += (size_t)NEDGE;
    int*   RSRC = (int*)(ws + off); off += (size_t)NEDGE;
    float* WREV = ws + off; off += (size_t)NEDGE;
    float* ZROW = ws + off; off += NN_NODES;   // ZROW,PF,PB contiguous (zeroed together)
    float* PF = ws + off; off += NN_NODES;
    float* PB = ws + off; off += NN_NODES;
    float* DIAG = ws + off; off += NN_NODES;
    unsigned short* HNbf = (unsigned short*)(ws + off); off += (size_t)NN_NODES * D_H / 2;
    unsigned short* Z1bf = (unsigned short*)(ws + off); off += (size_t)NN_NODES * D_H / 2;
    unsigned short* Z2bf = (unsigned short*)(ws + off); off += (size_t)NN_NODES * D_H / 2;
    int* ECNT = (int*)(ws + off); off += NN_NODES;
    int* EPTR = (int*)(ws + off); off += NN_NODES + 1;
    int* ESRT = (int*)(ws + off); off += (size_t)E;

    const int EBi = (E + 255) / 256;

    // 1. setup: x1 + zero(ECNT, FCNT, ZROW/PF/PB)
    {
        int blocks = (NN_NODES * D_IN + 5 * NN_NODES + 255) / 256;
        setup_kernel<<<blocks, 256, 0, stream>>>(x, p_feat, p_shared, X1, ECNT, FCNT, ZROW);
    }
    // 2. indegree count
    ecount_kernel<<<EBi, 256, 0, stream>>>(edst, ECNT, E);
    // 3. scan + dinv
    scan_kernel<<<1, 256, 0, stream>>>(ECNT, EPTR, DINV);
    // 4. CSR fill || x1s = dinv*x1  [disjoint blocks]
    {
        int xblocks = (NN_NODES * D_IN + 255) / 256;
        efill_x1s_kernel<<<EBi + xblocks, 256, 0, stream>>>(esrc, edst, EPTR, ECNT, ESRT, E, EBi,
                                                            X1, DINV, X1S);
    }
    // 5. agg gather (pre-scaled) + h/hn -> bf16
    agg_hn_kernel<<<NN_NODES, 256, 0, stream>>>(X1, X1S, DINV, EPTR, ESRT, p_balance, HNbf);
    // 6. sim = hn @ hn^T + per-row group maxima  (XCD-swizzled)
    gemm_nt_mfma<0><<<256, 512, 0, stream>>>(HNbf, HNbf, SIM, nullptr, ROWGMAX);
    // 7. hierarchical topk + fused indegree count of selected
    topk_kernel<<<NN_NODES, 256, 0, stream>>>(SIM, ROWGMAX, VALS, IDX, FCNT);
    // 8. scan (FCNT -> RPTR, zeroes FCNT)
    scan_kernel<<<1, 256, 0, stream>>>(FCNT, RPTR, nullptr);
    // 9. fillrev+wedges || T1 = X1 @ W1 (+T1s)  [disjoint blocks]
    dual_fillrev_gemm<<<EBLK + 256, 256, 0, stream>>>(IDX, VALS, RPTR, FCNT, RROW, RSRC,
                                                      WREV, WFWD, X1, W1, T1, DINV, T1S);
    // 10. H1 = relu(prop(T1)+b1)  ||  G1 = relu(W@T1+b1)   [prop reads pre-scaled T1s]
    dual_prop_spmm<<<2 * NN_NODES, 256, 0, stream>>>(T1S, T1, DINV, EPTR, ESRT, IDX, WFWD,
                                                     RPTR, RSRC, WREV, b1, H1, G1, 1);
    // 11. T2 = H1 @ W2 (+T2s)  ||  T3 = G1 @ W2
    {
        dim3 g(D_H / BN, 2 * NN_NODES / BM);
        gemm_nn2x_kernel<<<g, 256, 0, stream>>>(H1, G1, W2, T2, T3, DINV, T2S);
    }
    // 12. Z1 = elu(prop(T2)+b2)  ||  Z2 = elu(W@T3+b2)   [prop reads pre-scaled T2s]
    dual_prop_spmm<<<2 * NN_NODES, 256, 0, stream>>>(T2S, T3, DINV, EPTR, ESRT, IDX, WFWD,
                                                     RPTR, RSRC, WREV, b2, Z1, Z2, 2);
    // 13. rownorm both -> bf16 + diag (single 3-way reduction)
    rownorm_diag_kernel<<<NN_NODES, 256, 0, stream>>>(Z1, Z2, Z1bf, Z2bf, DIAG);
    // 14. zrow: row-sums of exp(5 * z1n@z2n^T)  (XCD-swizzled)
    gemm_nt_mfma<1><<<256, 512, 0, stream>>>(Z1bf, Z2bf, nullptr, ZROW, nullptr);
    // 15. pf / pb
    {
        int blocks = (2 * NEDGE * 16 + 255) / 256;
        pfpb_edges<<<blocks, 256, 0, stream>>>(Z1bf, Z2bf, IDX, WFWD, RROW, RSRC, WREV, ZROW, PF, PB);
    }
    // 16. loss
    loss_kernel<<<1, 256, 0, stream>>>(DIAG, ZROW, PF, PB, (float*)d_out);
}